// Round 3
// baseline (478.628 us; speedup 1.0000x reference)
//
#include <hip/hip_runtime.h>
#include <hip/hip_bf16.h>

// WindowAttention B=2048, N=64, DIM=256, 1 head, scale=1/16.
// ALGEBRAIC FUSION: out = P@(V Wp^T) + bp, so fold proj into the V weights:
//   Wt = Wp@Wv (256x256), bt = Wp@bv  ->  qkv_gemm emits Vt~ = x Wt^T + bt
//   attention PV output IS the final output (+ proj_b).
// prep (x->bf16, Wq/Wk->bf16, Wt=Wp@Wv, bias table)
// -> qkv_gemm (async-LDS MFMA, V~ transposed, XCD-swizzled grid)
// -> attn (barrier-free: V direct from global, ldsP wave-private, fp32 out).

typedef __bf16 bf16x8_t __attribute__((ext_vector_type(8)));
typedef float floatx4_t __attribute__((ext_vector_type(4)));

#define MFMA16(a, b, c) __builtin_amdgcn_mfma_f32_16x16x32_bf16(a, b, c, 0, 0, 0)
#define NTOK 131072  // 2048 windows * 64 tokens

__device__ __forceinline__ void gld_lds16(const void* g, void* l) {
  __builtin_amdgcn_global_load_lds(
      (const __attribute__((address_space(1))) unsigned int*)g,
      (__attribute__((address_space(3))) unsigned int*)l, 16, 0, 0);
}

__device__ __forceinline__ void cvt8(const float* src, __bf16* dst) {
  float4 f0 = reinterpret_cast<const float4*>(src)[0];
  float4 f1 = reinterpret_cast<const float4*>(src)[1];
  bf16x8_t h;
  h[0] = (__bf16)f0.x; h[1] = (__bf16)f0.y; h[2] = (__bf16)f0.z; h[3] = (__bf16)f0.w;
  h[4] = (__bf16)f1.x; h[5] = (__bf16)f1.y; h[6] = (__bf16)f1.z; h[7] = (__bf16)f1.w;
  *reinterpret_cast<bf16x8_t*>(dst) = h;
}

// ------------- prep: x->bf16, Wq/Wk->bf16, Wt=Wp@Wv, bias table -------------
// blk <16384: x cvt | <16448: qkv_w rows 0-511 cvt | <16464: bias table
// | <16720: Wt row j (fp32 dot, bf16 out) + bt.
__global__ __launch_bounds__(256) void prep_kernel(
    const float* __restrict__ x, const float* __restrict__ qkv_w,
    const float* __restrict__ qkv_b, const float* __restrict__ proj_w,
    const float* __restrict__ theta_max,
    const float* __restrict__ a_p, const float* __restrict__ b_p,
    const float* __restrict__ a_r, const float* __restrict__ b_r,
    __bf16* __restrict__ xb, __bf16* __restrict__ wb,
    float* __restrict__ bias_ws, float* __restrict__ btl) {
  int blk = blockIdx.x, tid = threadIdx.x;
  if (blk < 16384) {
    int t = blk * 256 + tid;
    cvt8(&x[(size_t)t * 8], &xb[(size_t)t * 8]);
  } else if (blk < 16448) {
    int t = (blk - 16384) * 256 + tid;  // rows 0..511 of qkv_w (Q,K weights)
    cvt8(&qkv_w[(size_t)t * 8], &wb[(size_t)t * 8]);
  } else if (blk < 16464) {
    int t = (blk - 16448) * 256 + tid;  // 0..4095
    int i = t >> 6, j = t & 63;
    int rad = (i >> 3) - (j >> 3), az = (i & 7) - (j & 7);
    int azm = ((az % 15) + 15) % 15;
    int rdm = ((rad % 15) + 15) % 15;
    float az_ang = (float)az * 0.09817477042468103f;  // 2*pi/64
    float tm = theta_max[j >> 3];                     // broadcasts over column j
    float r_ang = (float)rad * tm * (1.0f / 64.0f);
    bias_ws[t] = a_p[azm] * cosf(az_ang) + b_p[azm] * sinf(az_ang) +
                 a_r[rdm] * cosf(r_ang) + b_r[rdm] * sinf(r_ang);
  } else {
    // Wt[j,k] = sum_d proj_w[j,d] * qkv_w[512+d, k]  (fp32, -> bf16)
    int j = blk - 16464;  // 0..255
    int k = tid;
    float s = 0.f;
    for (int d = 0; d < 256; ++d)
      s += proj_w[j * 256 + d] * qkv_w[(size_t)(512 + d) * 256 + k];
    wb[(size_t)(512 + j) * 256 + k] = (__bf16)s;
    if (tid == 0) {
      float sb = 0.f;
      for (int d = 0; d < 256; ++d) sb += proj_w[j * 256 + d] * qkv_b[512 + d];
      btl[j] = sb;
    }
  }
}

// ---------------- QKV GEMM: (131072x256)bf16 @ (768x256)^T -----------------
// 128x128 tile, BK=64, async global->LDS (16B), XOR-swizzled LDS (no pad).
// 1D grid 6144 with XCD swizzle: the 6 bn-blocks sharing an A-panel run on
// the SAME XCD. Rows 512-767 of wb hold Wt -> emits projected V~ into Vt.
__global__ __launch_bounds__(256, 4) void qkv_gemm_kernel(
    const __bf16* __restrict__ xb, const __bf16* __restrict__ wb,
    const float* __restrict__ qkv_b, const float* __restrict__ btl,
    __bf16* __restrict__ Qd, __bf16* __restrict__ Kd, __bf16* __restrict__ Vt) {
  __shared__ __align__(16) __bf16 aT[128 * 64];  // 16 KB, swizzled chunks
  __shared__ __align__(16) __bf16 bT[128 * 64];
  const int tid = threadIdx.x;
  const int wg = blockIdx.x;
  const int id = (wg & 7) * 768 + (wg >> 3);
  const int bm = id / 6, bn = id - bm * 6;
  const int lane = tid & 63, wave = tid >> 6;
  const int wm = (wave >> 1) * 64, wn = (wave & 1) * 64;
  const int l15 = lane & 15, quad = lane >> 4;

  floatx4_t acc[4][4] = {};

  for (int kt = 0; kt < 4; ++kt) {
#pragma unroll
    for (int i = 0; i < 4; ++i) {
      int L = tid + i * 256;               // chunk id 0..1023
      int row = L >> 3, sc = L & 7, c8 = sc ^ (row & 7);
      gld_lds16(&xb[(size_t)(bm * 128 + row) * 256 + kt * 64 + c8 * 8], &aT[L * 8]);
      gld_lds16(&wb[(size_t)(bn * 128 + row) * 256 + kt * 64 + c8 * 8], &bT[L * 8]);
    }
    __syncthreads();
#pragma unroll
    for (int kc = 0; kc < 2; ++kc) {
      bf16x8_t af[4], bfr[4];
#pragma unroll
      for (int r = 0; r < 4; ++r) {
        int row = wm + r * 16 + l15, c8 = kc * 4 + quad, sc = c8 ^ (row & 7);
        af[r] = *reinterpret_cast<const bf16x8_t*>(&aT[(row * 8 + sc) * 8]);
      }
#pragma unroll
      for (int c = 0; c < 4; ++c) {
        int row = wn + c * 16 + l15, c8 = kc * 4 + quad, sc = c8 ^ (row & 7);
        bfr[c] = *reinterpret_cast<const bf16x8_t*>(&bT[(row * 8 + sc) * 8]);
      }
#pragma unroll
      for (int r = 0; r < 4; ++r)
#pragma unroll
        for (int c = 0; c < 4; ++c) acc[r][c] = MFMA16(af[r], bfr[c], acc[r][c]);
    }
    __syncthreads();
  }
  // epilogue: n<256 -> Q row-major, <512 -> K row-major, else V~ TRANSPOSED
#pragma unroll
  for (int c = 0; c < 4; ++c) {
    int n = bn * 128 + wn + c * 16 + l15;
    float bias = (n < 512) ? qkv_b[n] : btl[n - 512];
    if (n < 512) {
      __bf16* outp = (n < 256) ? Qd : Kd;
      int d = n & 255;
#pragma unroll
      for (int r = 0; r < 4; ++r) {
        int m0 = bm * 128 + wm + r * 16 + quad * 4;
#pragma unroll
        for (int g = 0; g < 4; ++g)
          outp[(size_t)(m0 + g) * 256 + d] = (__bf16)(acc[r][c][g] + bias);
      }
    } else {
      int d = n - 512;
#pragma unroll
      for (int r = 0; r < 4; ++r) {
        int m0 = bm * 128 + wm + r * 16 + quad * 4;
#pragma unroll
        for (int g = 0; g < 4; ++g)
          Vt[(size_t)d * NTOK + m0 + g] = (__bf16)(acc[r][c][g] + bias);
      }
    }
  }
}

// ------ attention (final): barrier-free, one block per window, fp32 out -----
// Q/K/V~ direct from global (V~ 4x wave amplification absorbed by L2).
// ldsP is wave-private (each wave writes+reads only its own 16 rows).
// out = PV~ + proj_b  (proj folded into V~ weights).
#define VPITCH 72
__global__ __launch_bounds__(256, 4) void attn_kernel(
    const __bf16* __restrict__ Qd, const __bf16* __restrict__ Kd,
    const __bf16* __restrict__ Vt, const float* __restrict__ bias_ws,
    const float* __restrict__ proj_b, float* __restrict__ out) {
  __shared__ __align__(16) __bf16 ldsP[64 * VPITCH];  // 9 KB, wave-private rows
  const int b = blockIdx.x;
  const size_t base = (size_t)b * 64 * 256;
  const int tid = threadIdx.x;
  const int lane = tid & 63, wave = tid >> 6;
  const int l15 = lane & 15, quad = lane >> 4;

  // Q fragments direct from global (own 16 rows)
  bf16x8_t qf[8];
#pragma unroll
  for (int kc = 0; kc < 8; ++kc)
    qf[kc] = *reinterpret_cast<const bf16x8_t*>(
        &Qd[base + (wave * 16 + l15) * 256 + kc * 32 + quad * 8]);

  // S = (Q K^T)*scale + bias ; K fragments direct from global
  floatx4_t accs[4] = {};
#pragma unroll
  for (int ct = 0; ct < 4; ++ct)
#pragma unroll
    for (int kc = 0; kc < 8; ++kc) {
      bf16x8_t bfr = *reinterpret_cast<const bf16x8_t*>(
          &Kd[base + (ct * 16 + l15) * 256 + kc * 32 + quad * 8]);
      accs[ct] = MFMA16(qf[kc], bfr, accs[ct]);
    }

  // softmax per row (C-layout: row = wave*16 + quad*4 + g, col = ct*16 + l15)
  float p[4][4];
#pragma unroll
  for (int ct = 0; ct < 4; ++ct)
#pragma unroll
    for (int g = 0; g < 4; ++g) {
      int row = wave * 16 + quad * 4 + g;
      p[ct][g] = accs[ct][g] * 0.0625f + bias_ws[row * 64 + ct * 16 + l15];
    }
#pragma unroll
  for (int g = 0; g < 4; ++g) {
    float m = fmaxf(fmaxf(p[0][g], p[1][g]), fmaxf(p[2][g], p[3][g]));
#pragma unroll
    for (int off = 1; off < 16; off <<= 1) m = fmaxf(m, __shfl_xor(m, off, 64));
    float l = 0.f;
#pragma unroll
    for (int ct = 0; ct < 4; ++ct) {
      p[ct][g] = __expf(p[ct][g] - m);
      l += p[ct][g];
    }
#pragma unroll
    for (int off = 1; off < 16; off <<= 1) l += __shfl_xor(l, off, 64);
    float inv = 1.0f / l;
    int row = wave * 16 + quad * 4 + g;
#pragma unroll
    for (int ct = 0; ct < 4; ++ct)
      ldsP[row * VPITCH + ct * 16 + l15] = (__bf16)(p[ct][g] * inv);
  }
  // no __syncthreads: each wave reads only its own ldsP rows (lgkmcnt ordering)

  // O = P @ V~ : A = own P rows (LDS), B = V~ direct from global (d-major)
  floatx4_t acco[16] = {};
#pragma unroll
  for (int kc = 0; kc < 2; ++kc) {
    bf16x8_t af = *reinterpret_cast<const bf16x8_t*>(
        &ldsP[(wave * 16 + l15) * VPITCH + kc * 32 + quad * 8]);
#pragma unroll
    for (int ct = 0; ct < 16; ++ct) {
      int n = ct * 16 + l15;
      bf16x8_t bfr = *reinterpret_cast<const bf16x8_t*>(
          &Vt[(size_t)n * NTOK + b * 64 + kc * 32 + quad * 8]);
      acco[ct] = MFMA16(af, bfr, acco[ct]);
    }
  }
  // final write: out = acco + proj_b[col]  (fp32)
#pragma unroll
  for (int ct = 0; ct < 16; ++ct) {
    int col = ct * 16 + l15;
    float pbv = proj_b[col];
#pragma unroll
    for (int g = 0; g < 4; ++g) {
      int row = wave * 16 + quad * 4 + g;
      out[base + (size_t)row * 256 + col] = acco[ct][g] + pbv;
    }
  }
}

extern "C" void kernel_launch(void* const* d_in, const int* in_sizes, int n_in,
                              void* d_out, int out_size, void* d_ws, size_t ws_size,
                              hipStream_t stream) {
  const float* x = (const float*)d_in[0];
  const float* theta_max = (const float*)d_in[1];
  const float* qkv_w = (const float*)d_in[2];
  const float* qkv_b = (const float*)d_in[3];
  const float* proj_w = (const float*)d_in[4];
  const float* proj_b = (const float*)d_in[5];
  const float* a_p = (const float*)d_in[6];
  const float* b_p = (const float*)d_in[7];
  const float* a_r = (const float*)d_in[8];
  const float* b_r = (const float*)d_in[9];
  float* out = (float*)d_out;

  char* ws = (char*)d_ws;
  const size_t BUF = 67108864;  // 64 MiB: one (131072 x 256) bf16 buffer
  float* bias_ws = (float*)ws;                    // 16 KB
  float* btl = (float*)(ws + 16384);              // 1 KB (bt = Wp@bv)
  __bf16* wb = (__bf16*)(ws + 32768);             // 384 KB ([Wq;Wk;Wt])
  __bf16* xb = (__bf16*)(ws + 1048576);           // 64 MB
  __bf16* Vt = (__bf16*)(ws + 1048576 + BUF);     // 64 MB (projected V~)
  __bf16* Qd = (__bf16*)(ws + 1048576 + 2 * BUF); // 64 MB
  __bf16* Kd = (__bf16*)(ws + 1048576 + 3 * BUF); // 64 MB  (~257 MiB total,
                                                  //  confirmed fits in round 2)

  hipLaunchKernelGGL(prep_kernel, dim3(16720), dim3(256), 0, stream,
                     x, qkv_w, qkv_b, proj_w, theta_max, a_p, b_p, a_r, b_r,
                     xb, wb, bias_ws, btl);
  hipLaunchKernelGGL(qkv_gemm_kernel, dim3(6144), dim3(256), 0, stream,
                     xb, wb, qkv_b, btl, Qd, Kd, Vt);
  hipLaunchKernelGGL(attn_kernel, dim3(2048), dim3(256), 0, stream,
                     Qd, Kd, Vt, bias_ws, proj_b, out);
}